// Round 8
// baseline (304.655 us; speedup 1.0000x reference)
//
#include <hip/hip_runtime.h>
#include <hip/hip_bf16.h>

#define N_NODES 50000
#define N_EDGES 800000
#define N_RELS  8
#define NKEYS   400000       // nodes * rels
#define NTOT    400384       // 1564 * 256
#define NB1     1564         // NTOT / 256

typedef __attribute__((ext_vector_type(8))) short bf16x8;
typedef __attribute__((ext_vector_type(4))) float f32x4;

__device__ __forceinline__ unsigned short f2b(float f) {
    unsigned int u = __float_as_uint(f);
    u += 0x7fffu + ((u >> 16) & 1u);
    return (unsigned short)(u >> 16);
}

// ---- prep: cvt_h (blocks 0..6249) | cvt_w->frag layout (6250..6761) | hist2 (6762..9886) ----
__global__ void prep_kernel(const float* __restrict__ h, unsigned short* __restrict__ hb,
                            const float* __restrict__ w, unsigned short* __restrict__ wt2,
                            const int* __restrict__ dst, const int* __restrict__ et,
                            int* __restrict__ counts2) {
    int b = blockIdx.x;
    if (b < 6250) {
        int i = b * 256 + threadIdx.x;               // 1,600,000 float4 chunks
        float4 v = ((const float4*)h)[i];
        ushort4 o;
        o.x = f2b(v.x); o.y = f2b(v.y); o.z = f2b(v.z); o.w = f2b(v.w);
        ((ushort4*)hb)[i] = o;
    } else if (b < 6762) {
        int idx = (b - 6250) * 256 + threadIdx.x;    // 131072 = 8*128*128
        int r = idx >> 14;
        int k = (idx >> 7) & 127;
        int o = idx & 127;
        // wt2[r][o>>4][k>>3][o&15][k&7]
        int off = (r << 14) + ((o >> 4) << 11) + ((k >> 3) << 7) + ((o & 15) << 3) + (k & 7);
        wt2[off] = f2b(w[idx]);
    } else {
        int e = (b - 6762) * 256 + threadIdx.x;      // 800000
        atomicAdd(&counts2[dst[e] * 8 + et[e]], 1);
    }
}

// ---- scan phase 1: per-block exclusive scan over NTOT keys ----
__global__ void scan1_kernel(const int* __restrict__ counts, int* __restrict__ partial,
                             int* __restrict__ bsum) {
    __shared__ int tmp[256];
    int i = blockIdx.x * 256 + threadIdx.x;          // grid exact: NB1
    int v = counts[i];
    tmp[threadIdx.x] = v;
    __syncthreads();
    #pragma unroll
    for (int off = 1; off < 256; off <<= 1) {
        int t = (threadIdx.x >= off) ? tmp[threadIdx.x - off] : 0;
        __syncthreads();
        tmp[threadIdx.x] += t;
        __syncthreads();
    }
    partial[i] = tmp[threadIdx.x] - v;               // exclusive
    if (threadIdx.x == 255) bsum[blockIdx.x] = tmp[255];
}

// ---- scan phase 2: exclusive scan of NB1 block sums (single block, chunked) ----
__global__ void scan2_kernel(int* __restrict__ bsum) {
    __shared__ int tmp[256];
    int run = 0;
    for (int c = 0; c < NB1; c += 256) {
        int i = c + threadIdx.x;
        int v = (i < NB1) ? bsum[i] : 0;
        tmp[threadIdx.x] = v;
        __syncthreads();
        #pragma unroll
        for (int off = 1; off < 256; off <<= 1) {
            int t = (threadIdx.x >= off) ? tmp[threadIdx.x - off] : 0;
            __syncthreads();
            tmp[threadIdx.x] += t;
            __syncthreads();
        }
        if (i < NB1) bsum[i] = run + tmp[threadIdx.x] - v;
        int tot = tmp[255];
        __syncthreads();
        run += tot;
    }
}

// ---- scan phase 3: add block offsets; init row_start2 + cursor2 ----
__global__ void scan3_kernel(const int* __restrict__ partial, const int* __restrict__ bsum,
                             int* __restrict__ row_start2, int* __restrict__ cursor2) {
    int i = blockIdx.x * 256 + threadIdx.x;          // grid exact: NB1
    int rs = partial[i] + bsum[i >> 8];
    if (i <= NKEYS) row_start2[i] = rs;              // row_start2[NKEYS] == N_EDGES
    if (i < NKEYS) cursor2[i] = rs;
}

// ---- scatter into (dst,rel)-sorted order; meta.x = hb row byte offset ----
__global__ void scatter_kernel(const int* __restrict__ src, const int* __restrict__ dst,
                               const int* __restrict__ et, const float* __restrict__ en,
                               int* __restrict__ cursor2, int2* __restrict__ meta) {
    int e = blockIdx.x * 256 + threadIdx.x;          // grid exact: 3125
    int key = dst[e] * 8 + et[e];
    int pos = atomicAdd(&cursor2[key], 1);
    meta[pos] = make_int2(src[e] << 8, __float_as_int(en[e]));
}

// ---- fused: gather-aggregate 16 nodes into LDS, then mini-GEMM vs wt2 (L2-hot),
//      fused bias+relu epilogue. Blocks: 3125 x 256 thr. LDS 32 KB. ----
__global__ __launch_bounds__(256) void fused_kernel(const char* __restrict__ hb,
                                                    const int2* __restrict__ meta,
                                                    const int* __restrict__ row_start2,
                                                    const char* __restrict__ wt2,
                                                    const float* __restrict__ bias,
                                                    float* __restrict__ out) {
    __shared__ char Bt[16 * 2048];    // 16 nodes x (8 rel x 128 k) bf16, XOR-chunk swizzle
    const int tid = threadIdx.x;
    const int wave = tid >> 6, lane = tid & 63;
    const int m16 = lane & 15, quad = lane >> 4;
    const int n0 = blockIdx.x * 16;

    // ---- phase 1: each wave aggregates 4 nodes ----
    for (int i = 0; i < 4; ++i) {
        int node = n0 + wave * 4 + i;
        int lrow = wave * 4 + i;
        int rs[9];
        #pragma unroll
        for (int r = 0; r < 9; ++r) rs[r] = row_start2[node * 8 + r];

        float2 acc[N_RELS];
        #pragma unroll
        for (int r = 0; r < N_RELS; ++r) acc[r] = make_float2(0.f, 0.f);

        for (int base = rs[0]; base < rs[8]; base += 64) {
            int hi = rs[8]; if (hi > base + 64) hi = base + 64;
            int2 m = make_int2(0, 0);
            if (base + lane < rs[8]) m = meta[base + lane];
            #pragma unroll
            for (int r = 0; r < N_RELS; ++r) {
                int ks = rs[r] > base ? rs[r] : base;
                int ke = rs[r + 1] < hi ? rs[r + 1] : hi;
                for (int k = ks; k < ke; ++k) {
                    int off = __shfl(m.x, k - base);
                    float w = __uint_as_float(__shfl(m.y, k - base));
                    unsigned int v = *(const unsigned int*)(hb + off + lane * 4);
                    acc[r].x += __uint_as_float(v << 16) * w;
                    acc[r].y += __uint_as_float(v & 0xffff0000u) * w;
                }
            }
        }
        // deposit row lrow: lane's chunk cs=lane>>2 stored at (cs ^ lrow), word lane&3
        int sw = (((lane >> 2) ^ lrow) << 4) + (lane & 3) * 4;
        #pragma unroll
        for (int r = 0; r < N_RELS; ++r) {
            unsigned int u = (unsigned int)f2b(acc[r].x) | ((unsigned int)f2b(acc[r].y) << 16);
            *(unsigned int*)(Bt + lrow * 2048 + r * 256 + sw) = u;
        }
    }
    __syncthreads();

    // ---- phase 2: 16-node x 128-o GEMM, K = 8 rel x 128; wave = 32-o stripe ----
    f32x4 acc2[2];
    acc2[0] = (f32x4){0.f, 0.f, 0.f, 0.f};
    acc2[1] = (f32x4){0.f, 0.f, 0.f, 0.f};
    const char* aBase = wt2 + (size_t)(wave * 2) * 4096 + m16 * 16;

    #pragma unroll
    for (int r = 0; r < N_RELS; ++r) {
        #pragma unroll
        for (int kk = 0; kk < 4; ++kk) {
            int c = kk * 4 + quad;
            bf16x8 b = *(const bf16x8*)(Bt + m16 * 2048 + r * 256 + ((c ^ m16) << 4));
            #pragma unroll
            for (int ogi = 0; ogi < 2; ++ogi) {
                bf16x8 a = *(const bf16x8*)(aBase + (size_t)r * 32768 + ogi * 4096 + c * 256);
                acc2[ogi] = __builtin_amdgcn_mfma_f32_16x16x32_bf16(a, b, acc2[ogi], 0, 0, 0);
            }
        }
    }

    // epilogue: D col(m16)=node, row(quad*4+reg)=o within og
    int n = n0 + m16;
    #pragma unroll
    for (int ogi = 0; ogi < 2; ++ogi) {
        int o = (wave * 2 + ogi) * 16 + quad * 4;
        float4 b4 = *(const float4*)&bias[o];
        float4 v;
        v.x = fmaxf(acc2[ogi][0] + b4.x, 0.f);
        v.y = fmaxf(acc2[ogi][1] + b4.y, 0.f);
        v.z = fmaxf(acc2[ogi][2] + b4.z, 0.f);
        v.w = fmaxf(acc2[ogi][3] + b4.w, 0.f);
        *(float4*)&out[(size_t)n * 128 + o] = v;
    }
}

extern "C" void kernel_launch(void* const* d_in, const int* in_sizes, int n_in,
                              void* d_out, int out_size, void* d_ws, size_t ws_size,
                              hipStream_t stream) {
    const float* h    = (const float*)d_in[0];
    const float* en   = (const float*)d_in[1];
    const int*   et   = (const int*)d_in[2];
    const int*   src  = (const int*)d_in[3];
    const int*   dst  = (const int*)d_in[4];
    const float* w    = (const float*)d_in[5];
    const float* bias = (const float*)d_in[6];
    float* out = (float*)d_out;

    char* ws = (char*)d_ws;
    unsigned short* hb  = (unsigned short*)(ws);                 //  12,800,000 B
    unsigned short* wt2 = (unsigned short*)(ws + 12800000);      //     262,144 B
    char* sbase = ws + 13062144;
    int*  counts2    = (int*)(sbase);                            // 1,601,536 B (NTOT) — reused as cursor2
    int*  partial2   = (int*)(sbase + 1601536);                  // 1,601,536 B
    int*  bsum       = (int*)(sbase + 3203072);                  //     6,400 B
    int*  row_start2 = (int*)(sbase + 3209472);                  // 1,600,004 B (NKEYS+1)
    int2* meta       = (int2*)(sbase + 4809728);                 // 6,400,000 B

    int* cursor2 = counts2;   // counts2 dead after scan1 — reuse

    (void)hipMemsetAsync(counts2, 0, NTOT * sizeof(int), stream);
    hipLaunchKernelGGL(prep_kernel, dim3(9887), dim3(256), 0, stream, h, hb, w, wt2, dst, et, counts2);
    hipLaunchKernelGGL(scan1_kernel, dim3(NB1), dim3(256), 0, stream, counts2, partial2, bsum);
    hipLaunchKernelGGL(scan2_kernel, dim3(1), dim3(256), 0, stream, bsum);
    hipLaunchKernelGGL(scan3_kernel, dim3(NB1), dim3(256), 0, stream, partial2, bsum, row_start2, cursor2);
    hipLaunchKernelGGL(scatter_kernel, dim3(N_EDGES / 256), dim3(256), 0, stream, src, dst, et, en, cursor2, meta);
    hipLaunchKernelGGL(fused_kernel, dim3(3125), dim3(256), 0, stream, (const char*)hb, meta, row_start2,
                       (const char*)wt2, bias, out);
}

// Round 9
// 255.262 us; speedup vs baseline: 1.1935x; 1.1935x over previous
//
#include <hip/hip_runtime.h>
#include <hip/hip_bf16.h>

#define N_NODES 50000
#define N_EDGES 800000
#define N_RELS  8
#define NKEYS   400000       // nodes * rels
#define NTOT    400384       // 1564 * 256
#define NB1     1564         // NTOT / 256

typedef __attribute__((ext_vector_type(8))) short bf16x8;
typedef __attribute__((ext_vector_type(4))) float f32x4;

typedef const __attribute__((address_space(1))) unsigned int* gptr_t;
typedef __attribute__((address_space(3))) unsigned int* lptr_t;

__device__ __forceinline__ unsigned short f2b(float f) {
    unsigned int u = __float_as_uint(f);
    u += 0x7fffu + ((u >> 16) & 1u);
    return (unsigned short)(u >> 16);
}

// ---- prep: cvt_h (blocks 0..6249) | cvt_w->frag layout (6250..6761) | hist2 (6762..9886) ----
__global__ void prep_kernel(const float* __restrict__ h, unsigned short* __restrict__ hb,
                            const float* __restrict__ w, unsigned short* __restrict__ wt2,
                            const int* __restrict__ dst, const int* __restrict__ et,
                            int* __restrict__ counts2) {
    int b = blockIdx.x;
    if (b < 6250) {
        int i = b * 256 + threadIdx.x;               // 1,600,000 float4 chunks
        float4 v = ((const float4*)h)[i];
        ushort4 o;
        o.x = f2b(v.x); o.y = f2b(v.y); o.z = f2b(v.z); o.w = f2b(v.w);
        ((ushort4*)hb)[i] = o;
    } else if (b < 6762) {
        int idx = (b - 6250) * 256 + threadIdx.x;    // 131072 = 8*128*128
        int r = idx >> 14;
        int k = (idx >> 7) & 127;
        int o = idx & 127;
        // wt2[r][o>>4][k>>3][o&15][k&7]
        int off = (r << 14) + ((o >> 4) << 11) + ((k >> 3) << 7) + ((o & 15) << 3) + (k & 7);
        wt2[off] = f2b(w[idx]);
    } else {
        int e = (b - 6762) * 256 + threadIdx.x;      // 800000
        atomicAdd(&counts2[dst[e] * 8 + et[e]], 1);
    }
}

// ---- single-pass decoupled-lookback exclusive scan over NTOT keys ----
// status[b]: (flag<<32)|aggregate ; flag 0=invalid 1=aggregate 2=prefix
__global__ __launch_bounds__(256) void lbscan_kernel(int* __restrict__ counts,
                                                     unsigned long long* __restrict__ status,
                                                     int* __restrict__ row_start2) {
    __shared__ int tmp[256];
    __shared__ int s_exc;
    const int b = blockIdx.x;
    const int tid = threadIdx.x;
    const int i = b * 256 + tid;
    int v = counts[i];
    tmp[tid] = v;
    __syncthreads();
    #pragma unroll
    for (int off = 1; off < 256; off <<= 1) {
        int t = (tid >= off) ? tmp[tid - off] : 0;
        __syncthreads();
        tmp[tid] += t;
        __syncthreads();
    }
    int inc = tmp[tid];
    int btot = tmp[255];
    if (tid == 0) {
        unsigned long long st = (b == 0) ? ((2ULL << 32) | (unsigned)btot)
                                         : ((1ULL << 32) | (unsigned)btot);
        atomicExch(&status[b], st);
        if (b == 0) s_exc = 0;
    }
    if (b > 0 && tid < 64) {
        int lane = tid;
        int exc = 0;
        int base = b - 64;
        while (true) {
            int j = base + lane;
            unsigned flag = 2u; unsigned val = 0u;
            if (j >= 0) {
                unsigned long long st;
                do { st = atomicAdd(&status[j], 0ULL); flag = (unsigned)(st >> 32); } while (flag == 0u);
                val = (unsigned)st;
            }
            unsigned long long pmask = __ballot(flag == 2u);
            int contrib;
            int done = (pmask != 0ULL);
            if (done) {
                int p = 63 - __clzll(pmask);         // most recent prefix in window
                contrib = (lane >= p) ? (int)val : 0;
            } else {
                contrib = (int)val;
            }
            #pragma unroll
            for (int s = 1; s < 64; s <<= 1) contrib += __shfl_xor(contrib, s);
            exc += contrib;
            if (done) break;
            base -= 64;
        }
        if (lane == 0) {
            s_exc = exc;
            atomicExch(&status[b], (2ULL << 32) | (unsigned)(exc + btot));
        }
    }
    __syncthreads();
    int rs = s_exc + inc - v;                        // exclusive
    if (i <= NKEYS) row_start2[i] = rs;              // row_start2[NKEYS] == N_EDGES
    if (i < NKEYS) counts[i] = rs;                   // counts reused as cursor2
}

// ---- scatter into (dst,rel)-sorted order; meta.x = hb row byte offset ----
__global__ void scatter_kernel(const int* __restrict__ src, const int* __restrict__ dst,
                               const int* __restrict__ et, const float* __restrict__ en,
                               int* __restrict__ cursor2, int2* __restrict__ meta) {
    int e = blockIdx.x * 256 + threadIdx.x;          // grid exact: 3125
    int key = dst[e] * 8 + et[e];
    int pos = atomicAdd(&cursor2[key], 1);
    meta[pos] = make_int2(src[e] << 8, __float_as_int(en[e]));
}

// ---- aggregate: one wave per dst node; readlane broadcast (no ds_bpermute),
//      2-edge unroll; writes agg[r][node][256B] bf16 with XOR-chunk swizzle ----
__global__ __launch_bounds__(256) void agg_kernel(const char* __restrict__ hb,
                                                  const int2* __restrict__ meta,
                                                  const int* __restrict__ row_start2,
                                                  char* __restrict__ agg) {
    int node = blockIdx.x * 4 + (threadIdx.x >> 6);  // 12500 * 4 = 50000
    int lane = threadIdx.x & 63;
    int rs[9];
    #pragma unroll
    for (int r = 0; r < 9; ++r) rs[r] = row_start2[node * 8 + r];

    float2 acc[N_RELS];
    #pragma unroll
    for (int r = 0; r < N_RELS; ++r) acc[r] = make_float2(0.f, 0.f);

    for (int base = rs[0]; base < rs[8]; base += 64) {
        int hi = rs[8] < base + 64 ? rs[8] : base + 64;
        int2 m = make_int2(0, 0);
        if (base + lane < rs[8]) m = meta[base + lane];
        #pragma unroll
        for (int r = 0; r < N_RELS; ++r) {
            int ks = (rs[r] > base ? rs[r] : base) - base;
            int ke = (rs[r + 1] < hi ? rs[r + 1] : hi) - base;
            int k = ks;
            for (; k + 2 <= ke; k += 2) {
                int o0 = __builtin_amdgcn_readlane(m.x, k);
                float w0 = __uint_as_float(__builtin_amdgcn_readlane(m.y, k));
                int o1 = __builtin_amdgcn_readlane(m.x, k + 1);
                float w1 = __uint_as_float(__builtin_amdgcn_readlane(m.y, k + 1));
                unsigned int v0 = *(const unsigned int*)(hb + o0 + lane * 4);
                unsigned int v1 = *(const unsigned int*)(hb + o1 + lane * 4);
                acc[r].x += __uint_as_float(v0 << 16) * w0;
                acc[r].y += __uint_as_float(v0 & 0xffff0000u) * w0;
                acc[r].x += __uint_as_float(v1 << 16) * w1;
                acc[r].y += __uint_as_float(v1 & 0xffff0000u) * w1;
            }
            if (k < ke) {
                int o0 = __builtin_amdgcn_readlane(m.x, k);
                float w0 = __uint_as_float(__builtin_amdgcn_readlane(m.y, k));
                unsigned int v0 = *(const unsigned int*)(hb + o0 + lane * 4);
                acc[r].x += __uint_as_float(v0 << 16) * w0;
                acc[r].y += __uint_as_float(v0 & 0xffff0000u) * w0;
            }
        }
    }
    // swizzled write: chunk cs = lane>>2 -> position (cs ^ (node&15))
    int sw = (((lane >> 2) ^ (node & 15)) << 4) + (lane & 3) * 4;
    #pragma unroll
    for (int r = 0; r < N_RELS; ++r) {
        unsigned int u = (unsigned int)f2b(acc[r].x) | ((unsigned int)f2b(acc[r].y) << 16);
        *(unsigned int*)(agg + ((size_t)(r * 50048 + node)) * 256 + sw) = u;
    }
}

// ---- gemm2: out[n][o] = relu(sum_{r,k} agg[r][n][k] * w[r][k][o] + bias[o])
//      64-node x 128-o tile; Ws(32KB)+Bs(16KB) staged via global_load_lds ----
__global__ __launch_bounds__(256) void gemm2_kernel(const char* __restrict__ agg,
                                                    const char* __restrict__ wt2,
                                                    const float* __restrict__ bias,
                                                    float* __restrict__ out) {
    __shared__ char Ws[32768];   // wt2[r] plane, fragment layout
    __shared__ char Bs[16384];   // 64 agg rows, source-swizzled
    const int n0 = blockIdx.x * 64;
    const int tid = threadIdx.x;
    const int wave = tid >> 6, lane = tid & 63;
    const int m16 = lane & 15, quad = lane >> 4;

    f32x4 acc[8];
    #pragma unroll
    for (int og = 0; og < 8; ++og) acc[og] = (f32x4){0.f, 0.f, 0.f, 0.f};

    for (int r = 0; r < N_RELS; ++r) {
        __syncthreads();
        const char* wsrc = wt2 + ((size_t)r << 15);
        const char* bsrc = agg + ((size_t)(r * 50048 + n0)) * 256;
        #pragma unroll
        for (int j = 0; j < 8; ++j) {
            int off = j * 4096 + wave * 1024 + lane * 16;
            __builtin_amdgcn_global_load_lds((gptr_t)(wsrc + off), (lptr_t)(Ws + j * 4096 + wave * 1024), 16, 0, 0);
        }
        #pragma unroll
        for (int j = 0; j < 4; ++j) {
            int off = j * 4096 + wave * 1024 + lane * 16;
            __builtin_amdgcn_global_load_lds((gptr_t)(bsrc + off), (lptr_t)(Bs + j * 4096 + wave * 1024), 16, 0, 0);
        }
        __syncthreads();
        #pragma unroll
        for (int kk = 0; kk < 4; ++kk) {
            int c = kk * 4 + quad;
            bf16x8 b = *(const bf16x8*)(Bs + (wave * 16 + m16) * 256 + ((c ^ m16) << 4));
            #pragma unroll
            for (int og = 0; og < 8; ++og) {
                bf16x8 a = *(const bf16x8*)(Ws + og * 4096 + c * 256 + m16 * 16);
                acc[og] = __builtin_amdgcn_mfma_f32_16x16x32_bf16(a, b, acc[og], 0, 0, 0);
            }
        }
    }

    int n = n0 + wave * 16 + m16;
    if (n < N_NODES) {
        #pragma unroll
        for (int og = 0; og < 8; ++og) {
            int o = og * 16 + quad * 4;
            float4 b4 = *(const float4*)&bias[o];
            float4 v;
            v.x = fmaxf(acc[og][0] + b4.x, 0.f);
            v.y = fmaxf(acc[og][1] + b4.y, 0.f);
            v.z = fmaxf(acc[og][2] + b4.z, 0.f);
            v.w = fmaxf(acc[og][3] + b4.w, 0.f);
            *(float4*)&out[(size_t)n * 128 + o] = v;
        }
    }
}

extern "C" void kernel_launch(void* const* d_in, const int* in_sizes, int n_in,
                              void* d_out, int out_size, void* d_ws, size_t ws_size,
                              hipStream_t stream) {
    const float* h    = (const float*)d_in[0];
    const float* en   = (const float*)d_in[1];
    const int*   et   = (const int*)d_in[2];
    const int*   src  = (const int*)d_in[3];
    const int*   dst  = (const int*)d_in[4];
    const float* w    = (const float*)d_in[5];
    const float* bias = (const float*)d_in[6];
    float* out = (float*)d_out;

    char* ws = (char*)d_ws;
    unsigned short* hb  = (unsigned short*)(ws);                 //  12,800,000 B
    unsigned short* wt2 = (unsigned short*)(ws + 12800000);      //     262,144 B
    char*           agg = ws + 13062144;                         // 102,498,304 B (8 * 50048 * 256)
    char* sbase = ws + 115560448;
    int*  counts2    = (int*)(sbase);                            // 1,601,536 B — reused as cursor2
    unsigned long long* status = (unsigned long long*)(sbase + 1601536);  // 12,800 B (zeroed w/ counts2)
    int*  row_start2 = (int*)(sbase + 1614336);                  // 1,600,256 B (NKEYS+1)
    int2* meta       = (int2*)(sbase + 3214592);                 // 6,400,000 B

    (void)hipMemsetAsync(counts2, 0, NTOT * sizeof(int) + NB1 * sizeof(unsigned long long), stream);
    hipLaunchKernelGGL(prep_kernel, dim3(9887), dim3(256), 0, stream, h, hb, w, wt2, dst, et, counts2);
    hipLaunchKernelGGL(lbscan_kernel, dim3(NB1), dim3(256), 0, stream, counts2, status, row_start2);
    hipLaunchKernelGGL(scatter_kernel, dim3(N_EDGES / 256), dim3(256), 0, stream, src, dst, et, en, counts2, meta);
    hipLaunchKernelGGL(agg_kernel, dim3(12500), dim3(256), 0, stream, (const char*)hb, meta, row_start2, agg);
    hipLaunchKernelGGL(gemm2_kernel, dim3(782), dim3(256), 0, stream, (const char*)agg, (const char*)wt2, bias, out);
}